// Round 5
// baseline (262.012 us; speedup 1.0000x reference)
//
#include <hip/hip_runtime.h>
#include <hip/hip_bf16.h>
#include <stdint.h>

#define BATCH 2
#define LQ 2048
#define LK 2048
#define DIM 1024
#define HEADS 8
#define DH 64
#define INNER 512  // HEADS*DH

typedef __attribute__((ext_vector_type(8))) short short8;
typedef __attribute__((ext_vector_type(4))) float f32x4;

__device__ __forceinline__ float bf2f(unsigned short u) {
    union { unsigned int i; float f; } v;
    v.i = ((unsigned int)u) << 16;
    return v.f;
}
__device__ __forceinline__ unsigned short f2bf(float f) {
    __hip_bfloat16 h = __float2bfloat16(f);
    return *reinterpret_cast<unsigned short*>(&h);
}
// raw v_exp_f32 (2^x); __expf would add a *log2e mul we fold into QSCALE
__device__ __forceinline__ float fexp2(float x) {
#if __has_builtin(__builtin_amdgcn_exp2f)
    return __builtin_amdgcn_exp2f(x);
#else
    return __expf(x * 0.69314718056f);
#endif
}
__device__ __forceinline__ void stc(unsigned short* C, size_t i, float v) { C[i] = f2bf(v); }
__device__ __forceinline__ void stc(float* C, size_t i, float v) { C[i] = v; }

// packed f32x2 -> bf16x2 (RNE), single instruction (T12 recipe; no builtin)
__device__ __forceinline__ unsigned cvtpk_bf16(float lo, float hi) {
    unsigned r;
    asm("v_cvt_pk_bf16_f32 %0, %1, %2" : "=v"(r) : "v"(lo), "v"(hi));
    return r;
}
// permlane swaps (gfx950): 32-swap: dst.hi32 <-> src.lo32 ; 16-swap: odd
// 16-rows of dst <-> even 16-rows of src.
__device__ __forceinline__ void perm32swap(unsigned& a, unsigned& b) {
#if __has_builtin(__builtin_amdgcn_permlane32_swap)
    auto r = __builtin_amdgcn_permlane32_swap(a, b, false, false);
    a = r[0]; b = r[1];
#else
    asm volatile("v_permlane32_swap_b32 %0, %1" : "+v"(a), "+v"(b));
#endif
}
__device__ __forceinline__ void perm16swap(unsigned& a, unsigned& b) {
#if __has_builtin(__builtin_amdgcn_permlane16_swap)
    auto r = __builtin_amdgcn_permlane16_swap(a, b, false, false);
    a = r[0]; b = r[1];
#else
    asm volatile("v_permlane16_swap_b32 %0, %1" : "+v"(a), "+v"(b));
#endif
}

// Direct global->LDS DMA, 16B/lane. LDS dest = wave-uniform base + lane*16.
typedef __attribute__((address_space(1))) const unsigned int gu32;
typedef __attribute__((address_space(3))) unsigned int lu32;
__device__ __forceinline__ void gload16(const void* g, void* l) {
    __builtin_amdgcn_global_load_lds((gu32*)g, (lu32*)l, 16, 0, 0);
}

// ---------------------------------------------------------------------------
// prep: fp32->bf16 copies (y=0..5, scalar RNE cvt) + mask bit-pack (y=6),
// one launch. (unchanged this round)
// ---------------------------------------------------------------------------
__global__ __launch_bounds__(256) void prep(
    const float* __restrict__ x,  const float* __restrict__ y,
    const float* __restrict__ wq, const float* __restrict__ wk,
    const float* __restrict__ wv, const float* __restrict__ wo,
    const float* __restrict__ mask,
    unsigned short* __restrict__ xb,  unsigned short* __restrict__ yb,
    unsigned short* __restrict__ wqb, unsigned short* __restrict__ wkb,
    unsigned short* __restrict__ wvb, unsigned short* __restrict__ wob,
    unsigned long long* __restrict__ mbits)
{
    if (blockIdx.y == 6) {
        const int wid = blockIdx.x * 4 + (threadIdx.x >> 6);   // 4096 waves
        const int lane = threadIdx.x & 63;
        for (int task = wid; task < BATCH * LQ * 8; task += 4096) {
            int row = task >> 3, g = task & 7;
            const float* mp = mask + (size_t)row * LK + g * 256;
            unsigned long long* ob = mbits + (size_t)row * (LK / 64) + g * 4;
            float v0 = mp[0 * 64 + lane];
            float v1 = mp[1 * 64 + lane];
            float v2 = mp[2 * 64 + lane];
            float v3 = mp[3 * 64 + lane];
            unsigned long long b0 = __ballot(v0 > 0.5f);
            unsigned long long b1 = __ballot(v1 > 0.5f);
            unsigned long long b2 = __ballot(v2 > 0.5f);
            unsigned long long b3 = __ballot(v3 > 0.5f);
            if (lane == 0) { ob[0] = b0; ob[1] = b1; ob[2] = b2; ob[3] = b3; }
        }
        return;
    }
    const float* src; unsigned short* dst; int n4;
    switch (blockIdx.y) {
        case 0: src = x;  dst = xb;  n4 = (BATCH * LQ * DIM) / 4; break;
        case 1: src = y;  dst = yb;  n4 = (BATCH * LK * DIM) / 4; break;
        case 2: src = wq; dst = wqb; n4 = (INNER * DIM) / 4; break;
        case 3: src = wk; dst = wkb; n4 = (INNER * DIM) / 4; break;
        case 4: src = wv; dst = wvb; n4 = (INNER * DIM) / 4; break;
        default: src = wo; dst = wob; n4 = (INNER * DIM) / 4; break;
    }
    const int stride = gridDim.x * 256;
    for (int i = blockIdx.x * 256 + threadIdx.x; i < n4; i += stride) {
        float4 f = ((const float4*)src)[i];
        ushort4 u;
        u.x = f2bf(f.x); u.y = f2bf(f.y); u.z = f2bf(f.z); u.w = f2bf(f.w);
        ((ushort4*)dst)[i] = u;
    }
}

// ---------------------------------------------------------------------------
// C = scale * (A[M,K] @ W[N,K]^T), bf16 in, fp32 accum.
// 128x128 tile, 8 waves (2x4), BK=64, swizzled global_load_lds staging,
// double-buffered, one barrier/K-tile. (unchanged this round)
// ---------------------------------------------------------------------------
template <int IM, int JN, int WR, int WC, typename TC, int EPI>
__device__ __forceinline__ void gemm_body(
    const unsigned short* __restrict__ A,
    const unsigned short* __restrict__ W,
    TC* __restrict__ C,
    int K, int N, float scale,
    unsigned short* SH)
{
    constexpr int THREADS = WR * WC * 64;
    constexpr int BM = WR * IM * 16;
    constexpr int BN = WC * JN * 16;
    constexpr int ACH = BM * 8;     // 16B chunks per A tile
    constexpr int BCH = BN * 8;
    constexpr int AUS = BM * 64;    // shorts per A buffer
    constexpr int BUS = BN * 64;

    unsigned short* As = SH;
    unsigned short* Bs = SH + 2 * AUS;

    const int tid = threadIdx.x;
    const int m0 = blockIdx.x * BM;
    const int n0 = blockIdx.y * BN;
    const int w = tid >> 6, lane = tid & 63;
    const int q4 = lane >> 4, l16 = lane & 15;
    const int wm = (w / WC) * (IM * 16), wn = (w % WC) * (JN * 16);
    const int sw = l16 & 7;

    f32x4 acc[IM][JN] = {};

#pragma unroll
    for (int i = 0; i < ACH / THREADS; ++i) {
        int s = tid + i * THREADS;
        int r = s >> 3, ch = (s & 7) ^ (r & 7);
        gload16(A + (size_t)(m0 + r) * K + ch * 8, As + (size_t)s * 8);
    }
#pragma unroll
    for (int i = 0; i < BCH / THREADS; ++i) {
        int s = tid + i * THREADS;
        int r = s >> 3, ch = (s & 7) ^ (r & 7);
        gload16(W + (size_t)(n0 + r) * K + ch * 8, Bs + (size_t)s * 8);
    }
    __syncthreads();

    const int nt = K / 64;
    for (int t = 0; t < nt; ++t) {
        const int curA = (t & 1) * AUS;
        const int curB = (t & 1) * BUS;
        if (t + 1 < nt) {
            int kk = (t + 1) * 64;
            const int nxtA = AUS - curA, nxtB = BUS - curB;
#pragma unroll
            for (int i = 0; i < ACH / THREADS; ++i) {
                int s = tid + i * THREADS;
                int r = s >> 3, ch = (s & 7) ^ (r & 7);
                gload16(A + (size_t)(m0 + r) * K + kk + ch * 8, As + nxtA + (size_t)s * 8);
            }
#pragma unroll
            for (int i = 0; i < BCH / THREADS; ++i) {
                int s = tid + i * THREADS;
                int r = s >> 3, ch = (s & 7) ^ (r & 7);
                gload16(W + (size_t)(n0 + r) * K + kk + ch * 8, Bs + nxtB + (size_t)s * 8);
            }
        }

#pragma unroll
        for (int ks = 0; ks < 2; ++ks) {
            const int kq = ((ks * 4 + q4) ^ sw) * 8;
            short8 a[IM], b[JN];
#pragma unroll
            for (int i = 0; i < IM; ++i)
                a[i] = *(const short8*)(As + curA + (wm + i * 16 + l16) * 64 + kq);
#pragma unroll
            for (int j = 0; j < JN; ++j)
                b[j] = *(const short8*)(Bs + curB + (wn + j * 16 + l16) * 64 + kq);
#pragma unroll
            for (int i = 0; i < IM; ++i)
#pragma unroll
                for (int j = 0; j < JN; ++j)
                    acc[i][j] = __builtin_amdgcn_mfma_f32_16x16x32_bf16(
                        a[i], b[j], acc[i][j], 0, 0, 0);
        }
        __syncthreads();
    }

    if (EPI == 0) {
        // C/D layout: col = lane&15, row = quad*4 + reg  [m89-verified]
#pragma unroll
        for (int i = 0; i < IM; ++i)
#pragma unroll
            for (int j = 0; j < JN; ++j)
#pragma unroll
                for (int r = 0; r < 4; ++r) {
                    int row = m0 + wm + i * 16 + q4 * 4 + r;
                    int col = n0 + wn + j * 16 + l16;
                    stc(C, (size_t)row * N + col, acc[i][j][r] * scale);
                }
    } else {
        // V-transpose epilogue into vt[((b*H+h)*DH+d)*LK + key].
        constexpr int KW = IM * 16;
        constexpr int DW = JN * 16;
        constexpr int TPS = KW + 8;
        unsigned short* TP = SH + w * (DW * TPS);
#pragma unroll
        for (int i = 0; i < IM; ++i)
#pragma unroll
            for (int j = 0; j < JN; ++j) {
                ushort4 u;
                u.x = f2bf(acc[i][j][0]); u.y = f2bf(acc[i][j][1]);
                u.z = f2bf(acc[i][j][2]); u.w = f2bf(acc[i][j][3]);
                *(ushort4*)(TP + (j * 16 + l16) * TPS + i * 16 + q4 * 4) = u;
            }
        const int keyflat = m0 + wm;
        const int bb = keyflat >> 11, key0 = keyflat & (LK - 1);
        const int hh = (n0 + wn) >> 6;
        const int dlow = (n0 + wn) & 63;
        constexpr int RCH = KW / 8;
        constexpr int NCH = DW * RCH;
#pragma unroll
        for (int p = 0; p < NCH / 64; ++p) {
            int c = p * 64 + lane;
            int dl = c / RCH, kc = c % RCH;
            uint4 v = *(const uint4*)(TP + dl * TPS + kc * 8);
            *(uint4*)((unsigned short*)C +
                ((size_t)((bb * HEADS + hh) * DH + dlow + dl)) * LK + key0 + kc * 8) = v;
        }
    }
}

// q scaled by 0.125*log2(e) so attn uses raw v_exp_f32 (2^x) directly.
#define QSCALE 0.18033688011112042f

__global__ __launch_bounds__(512) void proj_qkv(
    const unsigned short* __restrict__ xb, const unsigned short* __restrict__ yb,
    const unsigned short* __restrict__ wqb, const unsigned short* __restrict__ wkb,
    const unsigned short* __restrict__ wvb,
    unsigned short* __restrict__ qb, unsigned short* __restrict__ kb,
    unsigned short* __restrict__ vt)
{
    __shared__ __align__(16) unsigned short SH[4 * 128 * 64];  // 64 KB
    const int z = blockIdx.z;
    const unsigned short* A = (z == 0) ? xb : yb;
    const unsigned short* W = (z == 0) ? wqb : (z == 1) ? wkb : wvb;
    if (z == 2)
        gemm_body<4, 2, 2, 4, unsigned short, 1>(A, W, vt, DIM, INNER, 1.0f, SH);
    else
        gemm_body<4, 2, 2, 4, unsigned short, 0>(A, W, (z == 0) ? qb : kb, DIM, INNER,
                                                 (z == 0) ? QSCALE : 1.0f, SH);
}

__global__ __launch_bounds__(512) void gemm_out(
    const unsigned short* __restrict__ A,
    const unsigned short* __restrict__ W,
    float* __restrict__ C)
{
    __shared__ __align__(16) unsigned short SH[4 * 128 * 64];  // 64 KB
    gemm_body<4, 2, 2, 4, float, 0>(A, W, C, INNER, DIM, 1.0f, SH);
}

// ---------------------------------------------------------------------------
// Flash attention v4: LDS-FREE. K/V fragments read directly from global
// (L2-resident: K+V per (b,h) = 512 KB; FETCH_SIZE showed caches absorb the
// 32x re-read). Removes all staging, the ring buffer, and EVERY barrier in
// the main loop (waves fully independent -> latency hidden by occupancy,
// not lockstep). Per-lane fragment addresses = the old LDS indices without
// the XOR swizzle: 16 rows x 64B contiguous segments, L2-coalesced.
// 1-D grid with XCD-aware decode: h = bid&7 => all 64 blocks of a head land
// on one XCD => per-XCD L2 working set = 2 (b,h) slices = 1 MB << 4 MB.
// In-register P path (T12) unchanged. LDS = 17.4 KB parity-combine only.
// ---------------------------------------------------------------------------
__global__ __launch_bounds__(512, 4) void attn_mfma(
    const unsigned short* __restrict__ Q,
    const unsigned short* __restrict__ Kb,
    const unsigned short* __restrict__ Vt,
    const unsigned long long* __restrict__ Mb,
    unsigned short* __restrict__ O)
{
    __shared__ __align__(16) float xch[4 * 64 * 17];   // 17408 B

    const int tid = threadIdx.x;
    const int L = blockIdx.x;                 // 512 blocks, 1-D
    const int h = L & 7;                      // head == XCD slot
    const int jj = L >> 3;                    // 0..63
    const int b = jj >> 5;                    // batch
    const int q0 = (jj & 31) * 64;            // q-block
    const int w = tid >> 6, lane = tid & 63;
    const int g = w & 3;           // q-row group (16 rows)
    const int par = w >> 2;        // key-tile parity this wave computes
    const int q4 = lane >> 4, l16 = lane & 15;

    // Q as B-operand fragment: col q = l16, k-chunk = q4
    short8 qf[2];
    {
        const unsigned short* qp =
            Q + (size_t)(b * LQ + q0 + g * 16 + l16) * INNER + h * DH + q4 * 8;
        qf[0] = *(const short8*)(qp);
        qf[1] = *(const short8*)(qp + 32);
    }

    f32x4 o[4] = {};
    float lacc = 0.f;

    // per-lane fragment bases (row-strided, 16B each)
    const unsigned short* kfrag =
        Kb + (size_t)(b * LK + l16) * INNER + h * DH + q4 * 8;          // + key*INNER + ks*32
    const unsigned short* vfrag =
        Vt + (size_t)((b * HEADS + h) * DH + l16) * LK + q4 * 8;        // + dd*16*LK + key0 + ks*32
    const unsigned long long* mrow =
        Mb + (size_t)(b * LQ + q0 + g * 16 + l16) * (LK / 64);

    const int NT = LK / 64;   // 32 tiles; this wave does t = par, par+2, ...
    for (int t = par; t < NT; t += 2) {
        // ---- S^T = K Q^T : kf straight from global (L2) ----
        f32x4 s[4];
        short8 kf[4][2];
#pragma unroll
        for (int j = 0; j < 4; ++j)
#pragma unroll
            for (int ks = 0; ks < 2; ++ks)
                kf[j][ks] = *(const short8*)(kfrag
                    + (size_t)(t * 64 + j * 16) * INNER + ks * 32);
#pragma unroll
        for (int j = 0; j < 4; ++j) {
            s[j] = f32x4{0.f, 0.f, 0.f, 0.f};
#pragma unroll
            for (int ks = 0; ks < 2; ++ks)
                s[j] = __builtin_amdgcn_mfma_f32_16x16x32_bf16(kf[j][ks], qf[ks], s[j], 0, 0, 0);
        }

        // ---- p = masked ? 0 : 2^s ; pack to bf16 pairs in-register ----
        unsigned long long bsh = mrow[t] >> (q4 * 4);
        unsigned pk[8];
#pragma unroll
        for (int j = 0; j < 4; ++j) {
            unsigned nib = (unsigned)(bsh >> (16 * j)) & 0xFu;
            float p0 = (nib & 1u) ? 0.f : fexp2(s[j][0]);
            float p1 = (nib & 2u) ? 0.f : fexp2(s[j][1]);
            float p2 = (nib & 4u) ? 0.f : fexp2(s[j][2]);
            float p3 = (nib & 8u) ? 0.f : fexp2(s[j][3]);
            lacc += (p0 + p1) + (p2 + p3);
            pk[2 * j]     = cvtpk_bf16(p0, p1);
            pk[2 * j + 1] = cvtpk_bf16(p2, p3);
        }

        // ---- P^T B-frag via permlane (no LDS) ----
        short8 pf[2];
#pragma unroll
        for (int ks = 0; ks < 2; ++ks) {
            unsigned a0 = pk[4 * ks + 0], b0 = pk[4 * ks + 2];  // w0[j0], w0[j1]
            unsigned a1 = pk[4 * ks + 1], b1 = pk[4 * ks + 3];  // w1[j0], w1[j1]
            perm32swap(a0, b0); perm16swap(a0, b0);  // a0 = keys{0,1}, b0 = keys{4,5}
            perm32swap(a1, b1); perm16swap(a1, b1);  // a1 = keys{2,3}, b1 = keys{6,7}
            union { unsigned u[4]; short8 s8; } up;
            up.u[0] = a0; up.u[1] = a1; up.u[2] = b0; up.u[3] = b1;
            pf[ks] = up.s8;
        }

        // ---- O^T += V^T P^T : vf straight from global (L2) ----
#pragma unroll
        for (int ks = 0; ks < 2; ++ks) {
            short8 vf[4];
#pragma unroll
            for (int dd = 0; dd < 4; ++dd)
                vf[dd] = *(const short8*)(vfrag
                    + (size_t)(dd * 16) * LK + t * 64 + ks * 32);
#pragma unroll
            for (int dd = 0; dd < 4; ++dd)
                o[dd] = __builtin_amdgcn_mfma_f32_16x16x32_bf16(vf[dd], pf[ks], o[dd], 0, 0, 0);
        }
    }

    // ---- parity combine (exact: no-max softmax partial sums add) ----
    // stride 17 floats => odd stride, <=2-way conflict (free).
    if (par) {
        float* d = xch + (size_t)(g * 64 + lane) * 17;
#pragma unroll
        for (int dd = 0; dd < 4; ++dd)
#pragma unroll
            for (int r2 = 0; r2 < 4; ++r2) d[dd * 4 + r2] = o[dd][r2];
        d[16] = lacc;
    }
    __syncthreads();
    if (!par) {
        const float* d = xch + (size_t)(g * 64 + lane) * 17;
#pragma unroll
        for (int dd = 0; dd < 4; ++dd)
#pragma unroll
            for (int r2 = 0; r2 < 4; ++r2) o[dd][r2] += d[dd * 4 + r2];
        lacc += d[16];

        // reduce l across the 4 q4 groups (keys were split across q4)
        lacc += __shfl_xor(lacc, 16);
        lacc += __shfl_xor(lacc, 32);
        const float inv = 1.0f / lacc;

        // O^T layout: q = l16 (one row per lane), d = dd*16 + q4*4 + r
        unsigned short* orow =
            O + (size_t)(b * LQ + q0 + g * 16 + l16) * INNER + h * DH + q4 * 4;
#pragma unroll
        for (int dd = 0; dd < 4; ++dd) {
            ushort4 u;
            u.x = f2bf(o[dd][0] * inv); u.y = f2bf(o[dd][1] * inv);
            u.z = f2bf(o[dd][2] * inv); u.w = f2bf(o[dd][3] * inv);
            *(ushort4*)(orow + dd * 16) = u;
        }
    }
}

extern "C" void kernel_launch(void* const* d_in, const int* in_sizes, int n_in,
                              void* d_out, int out_size, void* d_ws, size_t ws_size,
                              hipStream_t stream) {
    const float* x    = (const float*)d_in[0];
    const float* y    = (const float*)d_in[1];
    const float* mask = (const float*)d_in[2];
    const float* Wq   = (const float*)d_in[3];
    const float* Wk   = (const float*)d_in[4];
    const float* Wv   = (const float*)d_in[5];
    const float* Wo   = (const float*)d_in[6];
    float* out = (float*)d_out;

    const size_t NX = (size_t)BATCH * LQ * DIM;    // 4.19M
    const size_t NS = (size_t)BATCH * LQ * INNER;  // 2.10M
    const size_t NW = (size_t)INNER * DIM;         // 0.52M
    unsigned short* xb  = (unsigned short*)d_ws;
    unsigned short* yb  = xb + NX;
    unsigned short* qb  = yb + NX;
    unsigned short* kb  = qb + NS;
    unsigned short* vt  = kb + NS;
    unsigned short* wqb = vt + NS;
    unsigned short* wkb = wqb + NW;
    unsigned short* wvb = wkb + NW;
    unsigned short* wob = wvb + NW;
    unsigned long long* mbits = (unsigned long long*)(wob + NW);
    unsigned short* ao  = xb;   // xb dead after proj
    // ws: 33.8 MB bf16 + 1 MB bits

    dim3 blk(256);
    prep<<<dim3(1024, 7), blk, 0, stream>>>(
        x, y, Wq, Wk, Wv, Wo, mask, xb, yb, wqb, wkb, wvb, wob, mbits);
    proj_qkv<<<dim3(4096 / 128, INNER / 128, 3), dim3(512), 0, stream>>>(
        xb, yb, wqb, wkb, wvb, qb, kb, vt);
    attn_mfma<<<dim3(512), dim3(512), 0, stream>>>(
        qb, kb, vt, mbits, ao);
    gemm_out<<<dim3(4096 / 128, DIM / 128), dim3(512), 0, stream>>>(ao, wob, out);
}

// Round 7
// 174.256 us; speedup vs baseline: 1.5036x; 1.5036x over previous
//
#include <hip/hip_runtime.h>
#include <hip/hip_bf16.h>
#include <stdint.h>

#define BATCH 2
#define LQ 2048
#define LK 2048
#define DIM 1024
#define HEADS 8
#define DH 64
#define INNER 512  // HEADS*DH

typedef __attribute__((ext_vector_type(8))) short short8;
typedef __attribute__((ext_vector_type(4))) float f32x4;

__device__ __forceinline__ float bf2f(unsigned short u) {
    union { unsigned int i; float f; } v;
    v.i = ((unsigned int)u) << 16;
    return v.f;
}
__device__ __forceinline__ unsigned short f2bf(float f) {
    __hip_bfloat16 h = __float2bfloat16(f);
    return *reinterpret_cast<unsigned short*>(&h);
}
// raw v_exp_f32 (2^x); __expf would add a *log2e mul we fold into QSCALE
__device__ __forceinline__ float fexp2(float x) {
#if __has_builtin(__builtin_amdgcn_exp2f)
    return __builtin_amdgcn_exp2f(x);
#else
    return __expf(x * 0.69314718056f);
#endif
}
__device__ __forceinline__ void stc(unsigned short* C, size_t i, float v) { C[i] = f2bf(v); }
__device__ __forceinline__ void stc(float* C, size_t i, float v) { C[i] = v; }

// packed f32x2 -> bf16x2 (RNE), single instruction (T12 recipe; no builtin)
__device__ __forceinline__ unsigned cvtpk_bf16(float lo, float hi) {
    unsigned r;
    asm("v_cvt_pk_bf16_f32 %0, %1, %2" : "=v"(r) : "v"(lo), "v"(hi));
    return r;
}
// permlane swaps (gfx950): 32-swap: dst.hi32 <-> src.lo32 ; 16-swap: odd
// 16-rows of dst <-> even 16-rows of src.
__device__ __forceinline__ void perm32swap(unsigned& a, unsigned& b) {
#if __has_builtin(__builtin_amdgcn_permlane32_swap)
    auto r = __builtin_amdgcn_permlane32_swap(a, b, false, false);
    a = r[0]; b = r[1];
#else
    asm volatile("v_permlane32_swap_b32 %0, %1" : "+v"(a), "+v"(b));
#endif
}
__device__ __forceinline__ void perm16swap(unsigned& a, unsigned& b) {
#if __has_builtin(__builtin_amdgcn_permlane16_swap)
    auto r = __builtin_amdgcn_permlane16_swap(a, b, false, false);
    a = r[0]; b = r[1];
#else
    asm volatile("v_permlane16_swap_b32 %0, %1" : "+v"(a), "+v"(b));
#endif
}

// Direct global->LDS DMA, 16B/lane. LDS dest = wave-uniform base + lane*16.
typedef __attribute__((address_space(1))) const unsigned int gu32;
typedef __attribute__((address_space(3))) unsigned int lu32;
__device__ __forceinline__ void gload16(const void* g, void* l) {
    __builtin_amdgcn_global_load_lds((gu32*)g, (lu32*)l, 16, 0, 0);
}

// ---------------------------------------------------------------------------
// prep: fp32->bf16 copies (y=0..5, scalar RNE cvt) + mask bit-pack (y=6),
// one launch. (unchanged this round)
// ---------------------------------------------------------------------------
__global__ __launch_bounds__(256) void prep(
    const float* __restrict__ x,  const float* __restrict__ y,
    const float* __restrict__ wq, const float* __restrict__ wk,
    const float* __restrict__ wv, const float* __restrict__ wo,
    const float* __restrict__ mask,
    unsigned short* __restrict__ xb,  unsigned short* __restrict__ yb,
    unsigned short* __restrict__ wqb, unsigned short* __restrict__ wkb,
    unsigned short* __restrict__ wvb, unsigned short* __restrict__ wob,
    unsigned long long* __restrict__ mbits)
{
    if (blockIdx.y == 6) {
        const int wid = blockIdx.x * 4 + (threadIdx.x >> 6);   // 4096 waves
        const int lane = threadIdx.x & 63;
        for (int task = wid; task < BATCH * LQ * 8; task += 4096) {
            int row = task >> 3, g = task & 7;
            const float* mp = mask + (size_t)row * LK + g * 256;
            unsigned long long* ob = mbits + (size_t)row * (LK / 64) + g * 4;
            float v0 = mp[0 * 64 + lane];
            float v1 = mp[1 * 64 + lane];
            float v2 = mp[2 * 64 + lane];
            float v3 = mp[3 * 64 + lane];
            unsigned long long b0 = __ballot(v0 > 0.5f);
            unsigned long long b1 = __ballot(v1 > 0.5f);
            unsigned long long b2 = __ballot(v2 > 0.5f);
            unsigned long long b3 = __ballot(v3 > 0.5f);
            if (lane == 0) { ob[0] = b0; ob[1] = b1; ob[2] = b2; ob[3] = b3; }
        }
        return;
    }
    const float* src; unsigned short* dst; int n4;
    switch (blockIdx.y) {
        case 0: src = x;  dst = xb;  n4 = (BATCH * LQ * DIM) / 4; break;
        case 1: src = y;  dst = yb;  n4 = (BATCH * LK * DIM) / 4; break;
        case 2: src = wq; dst = wqb; n4 = (INNER * DIM) / 4; break;
        case 3: src = wk; dst = wkb; n4 = (INNER * DIM) / 4; break;
        case 4: src = wv; dst = wvb; n4 = (INNER * DIM) / 4; break;
        default: src = wo; dst = wob; n4 = (INNER * DIM) / 4; break;
    }
    const int stride = gridDim.x * 256;
    for (int i = blockIdx.x * 256 + threadIdx.x; i < n4; i += stride) {
        float4 f = ((const float4*)src)[i];
        ushort4 u;
        u.x = f2bf(f.x); u.y = f2bf(f.y); u.z = f2bf(f.z); u.w = f2bf(f.w);
        ((ushort4*)dst)[i] = u;
    }
}

// ---------------------------------------------------------------------------
// C = scale * (A[M,K] @ W[N,K]^T), bf16 in, fp32 accum.
// 128x128 tile, 8 waves (2x4), BK=64, swizzled global_load_lds staging,
// double-buffered, one barrier/K-tile. (unchanged this round)
// ---------------------------------------------------------------------------
template <int IM, int JN, int WR, int WC, typename TC, int EPI>
__device__ __forceinline__ void gemm_body(
    const unsigned short* __restrict__ A,
    const unsigned short* __restrict__ W,
    TC* __restrict__ C,
    int K, int N, float scale,
    unsigned short* SH)
{
    constexpr int THREADS = WR * WC * 64;
    constexpr int BM = WR * IM * 16;
    constexpr int BN = WC * JN * 16;
    constexpr int ACH = BM * 8;     // 16B chunks per A tile
    constexpr int BCH = BN * 8;
    constexpr int AUS = BM * 64;    // shorts per A buffer
    constexpr int BUS = BN * 64;

    unsigned short* As = SH;
    unsigned short* Bs = SH + 2 * AUS;

    const int tid = threadIdx.x;
    const int m0 = blockIdx.x * BM;
    const int n0 = blockIdx.y * BN;
    const int w = tid >> 6, lane = tid & 63;
    const int q4 = lane >> 4, l16 = lane & 15;
    const int wm = (w / WC) * (IM * 16), wn = (w % WC) * (JN * 16);
    const int sw = l16 & 7;

    f32x4 acc[IM][JN] = {};

#pragma unroll
    for (int i = 0; i < ACH / THREADS; ++i) {
        int s = tid + i * THREADS;
        int r = s >> 3, ch = (s & 7) ^ (r & 7);
        gload16(A + (size_t)(m0 + r) * K + ch * 8, As + (size_t)s * 8);
    }
#pragma unroll
    for (int i = 0; i < BCH / THREADS; ++i) {
        int s = tid + i * THREADS;
        int r = s >> 3, ch = (s & 7) ^ (r & 7);
        gload16(W + (size_t)(n0 + r) * K + ch * 8, Bs + (size_t)s * 8);
    }
    __syncthreads();

    const int nt = K / 64;
    for (int t = 0; t < nt; ++t) {
        const int curA = (t & 1) * AUS;
        const int curB = (t & 1) * BUS;
        if (t + 1 < nt) {
            int kk = (t + 1) * 64;
            const int nxtA = AUS - curA, nxtB = BUS - curB;
#pragma unroll
            for (int i = 0; i < ACH / THREADS; ++i) {
                int s = tid + i * THREADS;
                int r = s >> 3, ch = (s & 7) ^ (r & 7);
                gload16(A + (size_t)(m0 + r) * K + kk + ch * 8, As + nxtA + (size_t)s * 8);
            }
#pragma unroll
            for (int i = 0; i < BCH / THREADS; ++i) {
                int s = tid + i * THREADS;
                int r = s >> 3, ch = (s & 7) ^ (r & 7);
                gload16(W + (size_t)(n0 + r) * K + kk + ch * 8, Bs + nxtB + (size_t)s * 8);
            }
        }

#pragma unroll
        for (int ks = 0; ks < 2; ++ks) {
            const int kq = ((ks * 4 + q4) ^ sw) * 8;
            short8 a[IM], b[JN];
#pragma unroll
            for (int i = 0; i < IM; ++i)
                a[i] = *(const short8*)(As + curA + (wm + i * 16 + l16) * 64 + kq);
#pragma unroll
            for (int j = 0; j < JN; ++j)
                b[j] = *(const short8*)(Bs + curB + (wn + j * 16 + l16) * 64 + kq);
#pragma unroll
            for (int i = 0; i < IM; ++i)
#pragma unroll
                for (int j = 0; j < JN; ++j)
                    acc[i][j] = __builtin_amdgcn_mfma_f32_16x16x32_bf16(
                        a[i], b[j], acc[i][j], 0, 0, 0);
        }
        __syncthreads();
    }

    if (EPI == 0) {
        // C/D layout: col = lane&15, row = quad*4 + reg  [m89-verified]
#pragma unroll
        for (int i = 0; i < IM; ++i)
#pragma unroll
            for (int j = 0; j < JN; ++j)
#pragma unroll
                for (int r = 0; r < 4; ++r) {
                    int row = m0 + wm + i * 16 + q4 * 4 + r;
                    int col = n0 + wn + j * 16 + l16;
                    stc(C, (size_t)row * N + col, acc[i][j][r] * scale);
                }
    } else {
        // V-transpose epilogue into vt[((b*H+h)*DH+d)*LK + key].
        constexpr int KW = IM * 16;
        constexpr int DW = JN * 16;
        constexpr int TPS = KW + 8;
        unsigned short* TP = SH + w * (DW * TPS);
#pragma unroll
        for (int i = 0; i < IM; ++i)
#pragma unroll
            for (int j = 0; j < JN; ++j) {
                ushort4 u;
                u.x = f2bf(acc[i][j][0]); u.y = f2bf(acc[i][j][1]);
                u.z = f2bf(acc[i][j][2]); u.w = f2bf(acc[i][j][3]);
                *(ushort4*)(TP + (j * 16 + l16) * TPS + i * 16 + q4 * 4) = u;
            }
        const int keyflat = m0 + wm;
        const int bb = keyflat >> 11, key0 = keyflat & (LK - 1);
        const int hh = (n0 + wn) >> 6;
        const int dlow = (n0 + wn) & 63;
        constexpr int RCH = KW / 8;
        constexpr int NCH = DW * RCH;
#pragma unroll
        for (int p = 0; p < NCH / 64; ++p) {
            int c = p * 64 + lane;
            int dl = c / RCH, kc = c % RCH;
            uint4 v = *(const uint4*)(TP + dl * TPS + kc * 8);
            *(uint4*)((unsigned short*)C +
                ((size_t)((bb * HEADS + hh) * DH + dlow + dl)) * LK + key0 + kc * 8) = v;
        }
    }
}

// q scaled by 0.125*log2(e) so attn uses raw v_exp_f32 (2^x) directly.
#define QSCALE 0.18033688011112042f

__global__ __launch_bounds__(512) void proj_qkv(
    const unsigned short* __restrict__ xb, const unsigned short* __restrict__ yb,
    const unsigned short* __restrict__ wqb, const unsigned short* __restrict__ wkb,
    const unsigned short* __restrict__ wvb,
    unsigned short* __restrict__ qb, unsigned short* __restrict__ kb,
    unsigned short* __restrict__ vt)
{
    __shared__ __align__(16) unsigned short SH[4 * 128 * 64];  // 64 KB
    const int z = blockIdx.z;
    const unsigned short* A = (z == 0) ? xb : yb;
    const unsigned short* W = (z == 0) ? wqb : (z == 1) ? wkb : wvb;
    if (z == 2)
        gemm_body<4, 2, 2, 4, unsigned short, 1>(A, W, vt, DIM, INNER, 1.0f, SH);
    else
        gemm_body<4, 2, 2, 4, unsigned short, 0>(A, W, (z == 0) ? qb : kb, DIM, INNER,
                                                 (z == 0) ? QSCALE : 1.0f, SH);
}

__global__ __launch_bounds__(512) void gemm_out(
    const unsigned short* __restrict__ A,
    const unsigned short* __restrict__ W,
    float* __restrict__ C)
{
    __shared__ __align__(16) unsigned short SH[4 * 128 * 64];  // 64 KB
    gemm_body<4, 2, 2, 4, float, 0>(A, W, C, INNER, DIM, 1.0f, SH);
}

// ---------------------------------------------------------------------------
// Flash attention v5: v3's proven LDS ring + T12 in-register P, restructured
// so each wave owns 32 q-rows (two 16-row fragment sets in regs). Every
// kf/vf ds_read_b128 now feeds TWO MFMAs (one per q-group) -> DS:MFMA ratio
// halves (the v3 bottleneck), and the two accumulator chains give 2x MFMA
// ILP. Block = 4 waves (qpos in {0,1} x par in {0,1}), 256 threads, same
// 64-row q-block, same 4-slot K/V ring, one barrier per 2-tile round.
// v4's LDS-free experiment is REVERTED (L2-latency-bound, 128 us).
// LDS = 32K (K) + 32K (V); parity combine reuses dead Ks (stride 35 floats).
// ---------------------------------------------------------------------------
#define AT_SLOT (64 * 64)

__global__ __launch_bounds__(256) void attn_mfma(
    const unsigned short* __restrict__ Q,
    const unsigned short* __restrict__ Kb,
    const unsigned short* __restrict__ Vt,
    const unsigned long long* __restrict__ Mb,
    unsigned short* __restrict__ O)
{
    __shared__ __align__(16) unsigned short Ks[4 * AT_SLOT];   // 32 KB
    __shared__ __align__(16) unsigned short Vs[4 * AT_SLOT];   // 32 KB

    const int tid = threadIdx.x;
    const int q0 = blockIdx.x * 64;
    const int h = blockIdx.y, b = blockIdx.z;
    const int w = tid >> 6, lane = tid & 63;
    const int qpos = w & 1;        // 32-row q-half of the block
    const int par = w >> 1;        // key-tile parity this wave computes
    const int q4 = lane >> 4, l16 = lane & 15;
    const int sw = l16 & 7;

    // Q as B-operand fragments for both 16-row groups: col q = l16
    short8 qf[2][2];
#pragma unroll
    for (int gg = 0; gg < 2; ++gg) {
        const unsigned short* qp =
            Q + (size_t)(b * LQ + q0 + qpos * 32 + gg * 16 + l16) * INNER + h * DH + q4 * 8;
        qf[gg][0] = *(const short8*)(qp);
        qf[gg][1] = *(const short8*)(qp + 32);
    }

    f32x4 o[2][4] = {};
    float lacc[2] = {0.f, 0.f};

    const unsigned short* kbase = Kb + (size_t)(b * LK) * INNER + h * DH;
    const unsigned short* vbase = Vt + (size_t)((b * HEADS + h) * DH) * LK;
    const unsigned long long* mrow[2];
#pragma unroll
    for (int gg = 0; gg < 2; ++gg)
        mrow[gg] = Mb + (size_t)(b * LQ + q0 + qpos * 32 + gg * 16 + l16) * (LK / 64);

    // staging coords: 256 threads stage a 64x64 tile in two half-passes
    const int r0 = tid >> 3, ch0 = (tid & 7) ^ (r0 & 7);
    const int st1 = tid + 256;
    const int r1 = st1 >> 3, ch1 = (st1 & 7) ^ (r1 & 7);

    // prologue: tiles 0,1 -> slots 0,1
#pragma unroll
    for (int tn = 0; tn < 2; ++tn) {
        gload16(kbase + (size_t)(tn * 64 + r0) * INNER + ch0 * 8,
                Ks + tn * AT_SLOT + (size_t)tid * 8);
        gload16(kbase + (size_t)(tn * 64 + r1) * INNER + ch1 * 8,
                Ks + tn * AT_SLOT + (size_t)st1 * 8);
        gload16(vbase + (size_t)r0 * LK + tn * 64 + ch0 * 8,
                Vs + tn * AT_SLOT + (size_t)tid * 8);
        gload16(vbase + (size_t)r1 * LK + tn * 64 + ch1 * 8,
                Vs + tn * AT_SLOT + (size_t)st1 * 8);
    }
    __syncthreads();

    const int NR = LK / 128;   // 16 rounds, 2 tiles each
    for (int rd = 0; rd < NR; ++rd) {
        if (rd + 1 < NR) {
#pragma unroll
            for (int i = 0; i < 2; ++i) {
                const int tn = 2 * rd + 2 + i;
                const int sl = tn & 3;
                const int kn = tn * 64;
                gload16(kbase + (size_t)(kn + r0) * INNER + ch0 * 8,
                        Ks + sl * AT_SLOT + (size_t)tid * 8);
                gload16(kbase + (size_t)(kn + r1) * INNER + ch1 * 8,
                        Ks + sl * AT_SLOT + (size_t)st1 * 8);
                gload16(vbase + (size_t)r0 * LK + kn + ch0 * 8,
                        Vs + sl * AT_SLOT + (size_t)tid * 8);
                gload16(vbase + (size_t)r1 * LK + kn + ch1 * 8,
                        Vs + sl * AT_SLOT + (size_t)st1 * 8);
            }
        }
        const int t = 2 * rd + par;
        const int cur = (t & 3) * AT_SLOT;

        // ---- S^T = K Q^T, both q-groups per kf read ----
        f32x4 s[2][4];
#pragma unroll
        for (int j = 0; j < 4; ++j) {
            s[0][j] = f32x4{0.f, 0.f, 0.f, 0.f};
            s[1][j] = f32x4{0.f, 0.f, 0.f, 0.f};
#pragma unroll
            for (int ks = 0; ks < 2; ++ks) {
                short8 kf = *(const short8*)(Ks + cur + (j * 16 + l16) * 64
                                             + (((ks * 4 + q4) ^ sw) * 8));
                s[0][j] = __builtin_amdgcn_mfma_f32_16x16x32_bf16(kf, qf[0][ks], s[0][j], 0, 0, 0);
                s[1][j] = __builtin_amdgcn_mfma_f32_16x16x32_bf16(kf, qf[1][ks], s[1][j], 0, 0, 0);
            }
        }

        // ---- p = masked ? 0 : 2^s ; pack + permlane per q-group (T12) ----
        short8 pf[2][2];
#pragma unroll
        for (int gg = 0; gg < 2; ++gg) {
            unsigned long long bsh = mrow[gg][t] >> (q4 * 4);
            unsigned pk[8];
#pragma unroll
            for (int j = 0; j < 4; ++j) {
                unsigned nib = (unsigned)(bsh >> (16 * j)) & 0xFu;
                float p0 = (nib & 1u) ? 0.f : fexp2(s[gg][j][0]);
                float p1 = (nib & 2u) ? 0.f : fexp2(s[gg][j][1]);
                float p2 = (nib & 4u) ? 0.f : fexp2(s[gg][j][2]);
                float p3 = (nib & 8u) ? 0.f : fexp2(s[gg][j][3]);
                lacc[gg] += (p0 + p1) + (p2 + p3);
                pk[2 * j]     = cvtpk_bf16(p0, p1);
                pk[2 * j + 1] = cvtpk_bf16(p2, p3);
            }
#pragma unroll
            for (int ks = 0; ks < 2; ++ks) {
                unsigned a0 = pk[4 * ks + 0], b0 = pk[4 * ks + 2];
                unsigned a1 = pk[4 * ks + 1], b1 = pk[4 * ks + 3];
                perm32swap(a0, b0); perm16swap(a0, b0);
                perm32swap(a1, b1); perm16swap(a1, b1);
                union { unsigned u[4]; short8 s8; } up;
                up.u[0] = a0; up.u[1] = a1; up.u[2] = b0; up.u[3] = b1;
                pf[gg][ks] = up.s8;
            }
        }

        // ---- O^T += V^T P^T, both q-groups per vf read ----
#pragma unroll
        for (int ks = 0; ks < 2; ++ks) {
#pragma unroll
            for (int dd = 0; dd < 4; ++dd) {
                short8 vf = *(const short8*)(Vs + cur + (dd * 16 + l16) * 64
                                             + (((ks * 4 + q4) ^ sw) * 8));
                o[0][dd] = __builtin_amdgcn_mfma_f32_16x16x32_bf16(vf, pf[0][ks], o[0][dd], 0, 0, 0);
                o[1][dd] = __builtin_amdgcn_mfma_f32_16x16x32_bf16(vf, pf[1][ks], o[1][dd], 0, 0, 0);
            }
        }
        __syncthreads();
    }

    // ---- parity combine (exact: no-max softmax partial sums add) ----
    // Ks dead; reuse. 34 floats/lane at stride 35 (odd => <=2-way, free).
    // Used: 2*64*35*4 = 17920 B <= 32 KB.
    float* xch = (float*)Ks;
    if (par) {
        float* d = xch + (size_t)(qpos * 64 + lane) * 35;
#pragma unroll
        for (int gg = 0; gg < 2; ++gg) {
#pragma unroll
            for (int dd = 0; dd < 4; ++dd)
#pragma unroll
                for (int r2 = 0; r2 < 4; ++r2)
                    d[gg * 16 + dd * 4 + r2] = o[gg][dd][r2];
            d[32 + gg] = lacc[gg];
        }
    }
    __syncthreads();
    if (!par) {
        const float* d = xch + (size_t)(qpos * 64 + lane) * 35;
#pragma unroll
        for (int gg = 0; gg < 2; ++gg) {
#pragma unroll
            for (int dd = 0; dd < 4; ++dd)
#pragma unroll
                for (int r2 = 0; r2 < 4; ++r2)
                    o[gg][dd][r2] += d[gg * 16 + dd * 4 + r2];
            lacc[gg] += d[32 + gg];
        }

        // reduce l across the 4 q4 groups (keys were split across q4)
#pragma unroll
        for (int gg = 0; gg < 2; ++gg) {
            lacc[gg] += __shfl_xor(lacc[gg], 16);
            lacc[gg] += __shfl_xor(lacc[gg], 32);
        }

        // O^T layout: q = l16 (one row per lane), d = dd*16 + q4*4 + r
#pragma unroll
        for (int gg = 0; gg < 2; ++gg) {
            const float inv = 1.0f / lacc[gg];
            unsigned short* orow =
                O + (size_t)(b * LQ + q0 + qpos * 32 + gg * 16 + l16) * INNER + h * DH + q4 * 4;
#pragma unroll
            for (int dd = 0; dd < 4; ++dd) {
                ushort4 u;
                u.x = f2bf(o[gg][dd][0] * inv); u.y = f2bf(o[gg][dd][1] * inv);
                u.z = f2bf(o[gg][dd][2] * inv); u.w = f2bf(o[gg][dd][3] * inv);
                *(ushort4*)(orow + dd * 16) = u;
            }
        }
    }
}

extern "C" void kernel_launch(void* const* d_in, const int* in_sizes, int n_in,
                              void* d_out, int out_size, void* d_ws, size_t ws_size,
                              hipStream_t stream) {
    const float* x    = (const float*)d_in[0];
    const float* y    = (const float*)d_in[1];
    const float* mask = (const float*)d_in[2];
    const float* Wq   = (const float*)d_in[3];
    const float* Wk   = (const float*)d_in[4];
    const float* Wv   = (const float*)d_in[5];
    const float* Wo   = (const float*)d_in[6];
    float* out = (float*)d_out;

    const size_t NX = (size_t)BATCH * LQ * DIM;    // 4.19M
    const size_t NS = (size_t)BATCH * LQ * INNER;  // 2.10M
    const size_t NW = (size_t)INNER * DIM;         // 0.52M
    unsigned short* xb  = (unsigned short*)d_ws;
    unsigned short* yb  = xb + NX;
    unsigned short* qb  = yb + NX;
    unsigned short* kb  = qb + NS;
    unsigned short* vt  = kb + NS;
    unsigned short* wqb = vt + NS;
    unsigned short* wkb = wqb + NW;
    unsigned short* wvb = wkb + NW;
    unsigned short* wob = wvb + NW;
    unsigned long long* mbits = (unsigned long long*)(wob + NW);
    unsigned short* ao  = xb;   // xb dead after proj
    // ws: 33.8 MB bf16 + 1 MB bits

    dim3 blk(256);
    prep<<<dim3(1024, 7), blk, 0, stream>>>(
        x, y, Wq, Wk, Wv, Wo, mask, xb, yb, wqb, wkb, wvb, wob, mbits);
    proj_qkv<<<dim3(4096 / 128, INNER / 128, 3), dim3(512), 0, stream>>>(
        xb, yb, wqb, wkb, wvb, qb, kb, vt);
    attn_mfma<<<dim3(LQ / 64, HEADS, BATCH), dim3(256), 0, stream>>>(
        qb, kb, vt, mbits, ao);
    gemm_out<<<dim3(4096 / 128, DIM / 128), dim3(512), 0, stream>>>(ao, wob, out);
}

// Round 10
// 174.047 us; speedup vs baseline: 1.5054x; 1.0012x over previous
//
#include <hip/hip_runtime.h>
#include <hip/hip_bf16.h>
#include <stdint.h>

#define BATCH 2
#define LQ 2048
#define LK 2048
#define DIM 1024
#define HEADS 8
#define DH 64
#define INNER 512  // HEADS*DH

typedef __attribute__((ext_vector_type(8))) short short8;
typedef __attribute__((ext_vector_type(4))) float f32x4;

__device__ __forceinline__ float bf2f(unsigned short u) {
    union { unsigned int i; float f; } v;
    v.i = ((unsigned int)u) << 16;
    return v.f;
}
__device__ __forceinline__ unsigned short f2bf(float f) {
    __hip_bfloat16 h = __float2bfloat16(f);
    return *reinterpret_cast<unsigned short*>(&h);
}
// raw v_exp_f32 (2^x); __expf would add a *log2e mul we fold into QSCALE
__device__ __forceinline__ float fexp2(float x) {
#if __has_builtin(__builtin_amdgcn_exp2f)
    return __builtin_amdgcn_exp2f(x);
#else
    return __expf(x * 0.69314718056f);
#endif
}
__device__ __forceinline__ void stc(unsigned short* C, size_t i, float v) { C[i] = f2bf(v); }
__device__ __forceinline__ void stc(float* C, size_t i, float v) { C[i] = v; }

// packed f32x2 -> bf16x2 (RNE), single instruction (T12 recipe; no builtin)
__device__ __forceinline__ unsigned cvtpk_bf16(float lo, float hi) {
    unsigned r;
    asm("v_cvt_pk_bf16_f32 %0, %1, %2" : "=v"(r) : "v"(lo), "v"(hi));
    return r;
}
// permlane swaps (gfx950): 32-swap: dst.hi32 <-> src.lo32 ; 16-swap: odd
// 16-rows of dst <-> even 16-rows of src.
__device__ __forceinline__ void perm32swap(unsigned& a, unsigned& b) {
#if __has_builtin(__builtin_amdgcn_permlane32_swap)
    auto r = __builtin_amdgcn_permlane32_swap(a, b, false, false);
    a = r[0]; b = r[1];
#else
    asm volatile("v_permlane32_swap_b32 %0, %1" : "+v"(a), "+v"(b));
#endif
}
__device__ __forceinline__ void perm16swap(unsigned& a, unsigned& b) {
#if __has_builtin(__builtin_amdgcn_permlane16_swap)
    auto r = __builtin_amdgcn_permlane16_swap(a, b, false, false);
    a = r[0]; b = r[1];
#else
    asm volatile("v_permlane16_swap_b32 %0, %1" : "+v"(a), "+v"(b));
#endif
}

// Direct global->LDS DMA, 16B/lane. LDS dest = wave-uniform base + lane*16.
typedef __attribute__((address_space(1))) const unsigned int gu32;
typedef __attribute__((address_space(3))) unsigned int lu32;
__device__ __forceinline__ void gload16(const void* g, void* l) {
    __builtin_amdgcn_global_load_lds((gu32*)g, (lu32*)l, 16, 0, 0);
}

// ---------------------------------------------------------------------------
// prep: fp32->bf16 copies (y=0..5, scalar RNE cvt) + mask bit-pack (y=6),
// one launch. (unchanged this round)
// ---------------------------------------------------------------------------
__global__ __launch_bounds__(256) void prep(
    const float* __restrict__ x,  const float* __restrict__ y,
    const float* __restrict__ wq, const float* __restrict__ wk,
    const float* __restrict__ wv, const float* __restrict__ wo,
    const float* __restrict__ mask,
    unsigned short* __restrict__ xb,  unsigned short* __restrict__ yb,
    unsigned short* __restrict__ wqb, unsigned short* __restrict__ wkb,
    unsigned short* __restrict__ wvb, unsigned short* __restrict__ wob,
    unsigned long long* __restrict__ mbits)
{
    if (blockIdx.y == 6) {
        const int wid = blockIdx.x * 4 + (threadIdx.x >> 6);   // 4096 waves
        const int lane = threadIdx.x & 63;
        for (int task = wid; task < BATCH * LQ * 8; task += 4096) {
            int row = task >> 3, g = task & 7;
            const float* mp = mask + (size_t)row * LK + g * 256;
            unsigned long long* ob = mbits + (size_t)row * (LK / 64) + g * 4;
            float v0 = mp[0 * 64 + lane];
            float v1 = mp[1 * 64 + lane];
            float v2 = mp[2 * 64 + lane];
            float v3 = mp[3 * 64 + lane];
            unsigned long long b0 = __ballot(v0 > 0.5f);
            unsigned long long b1 = __ballot(v1 > 0.5f);
            unsigned long long b2 = __ballot(v2 > 0.5f);
            unsigned long long b3 = __ballot(v3 > 0.5f);
            if (lane == 0) { ob[0] = b0; ob[1] = b1; ob[2] = b2; ob[3] = b3; }
        }
        return;
    }
    const float* src; unsigned short* dst; int n4;
    switch (blockIdx.y) {
        case 0: src = x;  dst = xb;  n4 = (BATCH * LQ * DIM) / 4; break;
        case 1: src = y;  dst = yb;  n4 = (BATCH * LK * DIM) / 4; break;
        case 2: src = wq; dst = wqb; n4 = (INNER * DIM) / 4; break;
        case 3: src = wk; dst = wkb; n4 = (INNER * DIM) / 4; break;
        case 4: src = wv; dst = wvb; n4 = (INNER * DIM) / 4; break;
        default: src = wo; dst = wob; n4 = (INNER * DIM) / 4; break;
    }
    const int stride = gridDim.x * 256;
    for (int i = blockIdx.x * 256 + threadIdx.x; i < n4; i += stride) {
        float4 f = ((const float4*)src)[i];
        ushort4 u;
        u.x = f2bf(f.x); u.y = f2bf(f.y); u.z = f2bf(f.z); u.w = f2bf(f.w);
        ((ushort4*)dst)[i] = u;
    }
}

// ---------------------------------------------------------------------------
// C = scale * (A[M,K] @ W[N,K]^T), bf16 in, fp32 accum.
// 128x128 tile, 8 waves (2x4), BK=64, swizzled global_load_lds staging,
// double-buffered, one barrier/K-tile. (unchanged this round)
// ---------------------------------------------------------------------------
template <int IM, int JN, int WR, int WC, typename TC, int EPI>
__device__ __forceinline__ void gemm_body(
    const unsigned short* __restrict__ A,
    const unsigned short* __restrict__ W,
    TC* __restrict__ C,
    int K, int N, float scale,
    unsigned short* SH)
{
    constexpr int THREADS = WR * WC * 64;
    constexpr int BM = WR * IM * 16;
    constexpr int BN = WC * JN * 16;
    constexpr int ACH = BM * 8;     // 16B chunks per A tile
    constexpr int BCH = BN * 8;
    constexpr int AUS = BM * 64;    // shorts per A buffer
    constexpr int BUS = BN * 64;

    unsigned short* As = SH;
    unsigned short* Bs = SH + 2 * AUS;

    const int tid = threadIdx.x;
    const int m0 = blockIdx.x * BM;
    const int n0 = blockIdx.y * BN;
    const int w = tid >> 6, lane = tid & 63;
    const int q4 = lane >> 4, l16 = lane & 15;
    const int wm = (w / WC) * (IM * 16), wn = (w % WC) * (JN * 16);
    const int sw = l16 & 7;

    f32x4 acc[IM][JN] = {};

#pragma unroll
    for (int i = 0; i < ACH / THREADS; ++i) {
        int s = tid + i * THREADS;
        int r = s >> 3, ch = (s & 7) ^ (r & 7);
        gload16(A + (size_t)(m0 + r) * K + ch * 8, As + (size_t)s * 8);
    }
#pragma unroll
    for (int i = 0; i < BCH / THREADS; ++i) {
        int s = tid + i * THREADS;
        int r = s >> 3, ch = (s & 7) ^ (r & 7);
        gload16(W + (size_t)(n0 + r) * K + ch * 8, Bs + (size_t)s * 8);
    }
    __syncthreads();

    const int nt = K / 64;
    for (int t = 0; t < nt; ++t) {
        const int curA = (t & 1) * AUS;
        const int curB = (t & 1) * BUS;
        if (t + 1 < nt) {
            int kk = (t + 1) * 64;
            const int nxtA = AUS - curA, nxtB = BUS - curB;
#pragma unroll
            for (int i = 0; i < ACH / THREADS; ++i) {
                int s = tid + i * THREADS;
                int r = s >> 3, ch = (s & 7) ^ (r & 7);
                gload16(A + (size_t)(m0 + r) * K + kk + ch * 8, As + nxtA + (size_t)s * 8);
            }
#pragma unroll
            for (int i = 0; i < BCH / THREADS; ++i) {
                int s = tid + i * THREADS;
                int r = s >> 3, ch = (s & 7) ^ (r & 7);
                gload16(W + (size_t)(n0 + r) * K + kk + ch * 8, Bs + nxtB + (size_t)s * 8);
            }
        }

#pragma unroll
        for (int ks = 0; ks < 2; ++ks) {
            const int kq = ((ks * 4 + q4) ^ sw) * 8;
            short8 a[IM], b[JN];
#pragma unroll
            for (int i = 0; i < IM; ++i)
                a[i] = *(const short8*)(As + curA + (wm + i * 16 + l16) * 64 + kq);
#pragma unroll
            for (int j = 0; j < JN; ++j)
                b[j] = *(const short8*)(Bs + curB + (wn + j * 16 + l16) * 64 + kq);
#pragma unroll
            for (int i = 0; i < IM; ++i)
#pragma unroll
                for (int j = 0; j < JN; ++j)
                    acc[i][j] = __builtin_amdgcn_mfma_f32_16x16x32_bf16(
                        a[i], b[j], acc[i][j], 0, 0, 0);
        }
        __syncthreads();
    }

    if (EPI == 0) {
        // C/D layout: col = lane&15, row = quad*4 + reg  [m89-verified]
#pragma unroll
        for (int i = 0; i < IM; ++i)
#pragma unroll
            for (int j = 0; j < JN; ++j)
#pragma unroll
                for (int r = 0; r < 4; ++r) {
                    int row = m0 + wm + i * 16 + q4 * 4 + r;
                    int col = n0 + wn + j * 16 + l16;
                    stc(C, (size_t)row * N + col, acc[i][j][r] * scale);
                }
    } else {
        // V-transpose epilogue into vt[((b*H+h)*DH+d)*LK + key].
        constexpr int KW = IM * 16;
        constexpr int DW = JN * 16;
        constexpr int TPS = KW + 8;
        unsigned short* TP = SH + w * (DW * TPS);
#pragma unroll
        for (int i = 0; i < IM; ++i)
#pragma unroll
            for (int j = 0; j < JN; ++j) {
                ushort4 u;
                u.x = f2bf(acc[i][j][0]); u.y = f2bf(acc[i][j][1]);
                u.z = f2bf(acc[i][j][2]); u.w = f2bf(acc[i][j][3]);
                *(ushort4*)(TP + (j * 16 + l16) * TPS + i * 16 + q4 * 4) = u;
            }
        const int keyflat = m0 + wm;
        const int bb = keyflat >> 11, key0 = keyflat & (LK - 1);
        const int hh = (n0 + wn) >> 6;
        const int dlow = (n0 + wn) & 63;
        constexpr int RCH = KW / 8;
        constexpr int NCH = DW * RCH;
#pragma unroll
        for (int p = 0; p < NCH / 64; ++p) {
            int c = p * 64 + lane;
            int dl = c / RCH, kc = c % RCH;
            uint4 v = *(const uint4*)(TP + dl * TPS + kc * 8);
            *(uint4*)((unsigned short*)C +
                ((size_t)((bb * HEADS + hh) * DH + dlow + dl)) * LK + key0 + kc * 8) = v;
        }
    }
}

// q scaled by 0.125*log2(e) so attn uses raw v_exp_f32 (2^x) directly.
#define QSCALE 0.18033688011112042f

__global__ __launch_bounds__(512) void proj_qkv(
    const unsigned short* __restrict__ xb, const unsigned short* __restrict__ yb,
    const unsigned short* __restrict__ wqb, const unsigned short* __restrict__ wkb,
    const unsigned short* __restrict__ wvb,
    unsigned short* __restrict__ qb, unsigned short* __restrict__ kb,
    unsigned short* __restrict__ vt)
{
    __shared__ __align__(16) unsigned short SH[4 * 128 * 64];  // 64 KB
    const int z = blockIdx.z;
    const unsigned short* A = (z == 0) ? xb : yb;
    const unsigned short* W = (z == 0) ? wqb : (z == 1) ? wkb : wvb;
    if (z == 2)
        gemm_body<4, 2, 2, 4, unsigned short, 1>(A, W, vt, DIM, INNER, 1.0f, SH);
    else
        gemm_body<4, 2, 2, 4, unsigned short, 0>(A, W, (z == 0) ? qb : kb, DIM, INNER,
                                                 (z == 0) ? QSCALE : 1.0f, SH);
}

__global__ __launch_bounds__(512) void gemm_out(
    const unsigned short* __restrict__ A,
    const unsigned short* __restrict__ W,
    float* __restrict__ C)
{
    __shared__ __align__(16) unsigned short SH[4 * 128 * 64];  // 64 KB
    gemm_body<4, 2, 2, 4, float, 0>(A, W, C, INNER, DIM, 1.0f, SH);
}

// ---------------------------------------------------------------------------
// Flash attention v6 = v3 (proven best: 8 waves x 512 thr, 4-slot ring, T12
// in-register P, parity split) + two low-risk deltas:
//  (1) T1 XCD swizzle: 1-D grid, h = bid&7 -> all 64 blocks of a head land
//      on one XCD (round-robin dispatch model); per-XCD L2 working set
//      drops 8 MB -> 1 MB. Attacks the 35.4 MB FETCH_SIZE (4x over-fetch).
//  (2) T5 setprio(1) around the QK and PV MFMA clusters (8 waves at
//      different parity phases -> scheduler has something to arbitrate).
// v5 (32 q-rows/wave, 4 waves) REVERTED: halved occupancy, +5 us.
// ---------------------------------------------------------------------------
#define AT_SLOT (64 * 64)

__global__ __launch_bounds__(512, 4) void attn_mfma(
    const unsigned short* __restrict__ Q,
    const unsigned short* __restrict__ Kb,
    const unsigned short* __restrict__ Vt,
    const unsigned long long* __restrict__ Mb,
    unsigned short* __restrict__ O)
{
    __shared__ __align__(16) unsigned short Ks[4 * AT_SLOT];   // 32 KB
    __shared__ __align__(16) unsigned short Vs[4 * AT_SLOT];   // 32 KB

    const int tid = threadIdx.x;
    // XCD-aware decode: consecutive bid -> different XCD (round-robin), so
    // h = bid&7 pins each head's 64 blocks to one XCD's L2.
    const int L = blockIdx.x;
    const int h = L & 7;
    const int jj = L >> 3;                    // 0..63
    const int b = jj >> 5;                    // batch
    const int q0 = (jj & 31) * 64;            // q-block
    const int w = tid >> 6, lane = tid & 63;
    const int g = w & 3;           // q-row group (16 rows)
    const int par = w >> 2;        // key-tile parity this wave computes
    const int q4 = lane >> 4, l16 = lane & 15;
    const int sw = l16 & 7;

    // Q as B-operand fragment: col q = l16, k-chunk = q4
    short8 qf[2];
    {
        const unsigned short* qp =
            Q + (size_t)(b * LQ + q0 + g * 16 + l16) * INNER + h * DH + q4 * 8;
        qf[0] = *(const short8*)(qp);
        qf[1] = *(const short8*)(qp + 32);
    }

    f32x4 o[4] = {};
    float lacc = 0.f;

    const unsigned short* kbase = Kb + (size_t)(b * LK) * INNER + h * DH;
    const unsigned short* vbase = Vt + (size_t)((b * HEADS + h) * DH) * LK;
    // one mask row per lane: q = l16
    const unsigned long long* mrow =
        Mb + (size_t)(b * LQ + q0 + g * 16 + l16) * (LK / 64);

    // per-thread staging coords: 512 threads stage one 64x64 tile per gload16
    const int rr = tid >> 3;
    const int ch = (tid & 7) ^ (rr & 7);

    // prologue: tiles 0,1 -> slots 0,1
#pragma unroll
    for (int tn = 0; tn < 2; ++tn) {
        gload16(kbase + (size_t)(tn * 64 + rr) * INNER + ch * 8,
                Ks + tn * AT_SLOT + (size_t)tid * 8);
        gload16(vbase + (size_t)rr * LK + tn * 64 + ch * 8,
                Vs + tn * AT_SLOT + (size_t)tid * 8);
    }
    __syncthreads();

    const int NR = LK / 128;   // 16 rounds, 2 tiles each
    for (int rd = 0; rd < NR; ++rd) {
        if (rd + 1 < NR) {
#pragma unroll
            for (int i = 0; i < 2; ++i) {
                const int tn = 2 * rd + 2 + i;
                const int sl = tn & 3;
                gload16(kbase + (size_t)(tn * 64 + rr) * INNER + ch * 8,
                        Ks + sl * AT_SLOT + (size_t)tid * 8);
                gload16(vbase + (size_t)rr * LK + tn * 64 + ch * 8,
                        Vs + sl * AT_SLOT + (size_t)tid * 8);
            }
        }
        const int t = 2 * rd + par;
        const int cur = (t & 3) * AT_SLOT;

        // ---- S^T = K Q^T (A = K rows, B = Q) ----
        f32x4 s[4];
        __builtin_amdgcn_s_setprio(1);
#pragma unroll
        for (int j = 0; j < 4; ++j) {
            s[j] = f32x4{0.f, 0.f, 0.f, 0.f};
#pragma unroll
            for (int ks = 0; ks < 2; ++ks) {
                short8 kf = *(const short8*)(Ks + cur + (j * 16 + l16) * 64
                                             + (((ks * 4 + q4) ^ sw) * 8));
                s[j] = __builtin_amdgcn_mfma_f32_16x16x32_bf16(kf, qf[ks], s[j], 0, 0, 0);
            }
        }
        __builtin_amdgcn_s_setprio(0);

        // ---- p = masked ? 0 : 2^s ; pack to bf16 pairs in-register ----
        // lane needs key bits {16j + 4*q4 + r}: shift out 4*q4, then nibbles.
        unsigned long long bsh = mrow[t] >> (q4 * 4);
        unsigned pk[8];
#pragma unroll
        for (int j = 0; j < 4; ++j) {
            unsigned nib = (unsigned)(bsh >> (16 * j)) & 0xFu;
            float p0 = (nib & 1u) ? 0.f : fexp2(s[j][0]);
            float p1 = (nib & 2u) ? 0.f : fexp2(s[j][1]);
            float p2 = (nib & 4u) ? 0.f : fexp2(s[j][2]);
            float p3 = (nib & 8u) ? 0.f : fexp2(s[j][3]);
            lacc += (p0 + p1) + (p2 + p3);
            pk[2 * j]     = cvtpk_bf16(p0, p1);
            pk[2 * j + 1] = cvtpk_bf16(p2, p3);
        }

        // ---- P^T B-frag via permlane (no LDS) ----
        short8 pf[2];
#pragma unroll
        for (int ks = 0; ks < 2; ++ks) {
            unsigned a0 = pk[4 * ks + 0], b0 = pk[4 * ks + 2];  // w0[j0], w0[j1]
            unsigned a1 = pk[4 * ks + 1], b1 = pk[4 * ks + 3];  // w1[j0], w1[j1]
            perm32swap(a0, b0); perm16swap(a0, b0);  // a0 = keys{0,1}, b0 = keys{4,5}
            perm32swap(a1, b1); perm16swap(a1, b1);  // a1 = keys{2,3}, b1 = keys{6,7}
            union { unsigned u[4]; short8 s8; } up;
            up.u[0] = a0; up.u[1] = a1; up.u[2] = b0; up.u[3] = b1;
            pf[ks] = up.s8;
        }

        // ---- O^T += V^T P^T (vf reads unchanged) ----
        __builtin_amdgcn_s_setprio(1);
#pragma unroll
        for (int ks = 0; ks < 2; ++ks) {
#pragma unroll
            for (int dd = 0; dd < 4; ++dd) {
                short8 vf = *(const short8*)(Vs + cur + (dd * 16 + l16) * 64
                                             + (((ks * 4 + q4) ^ sw) * 8));
                o[dd] = __builtin_amdgcn_mfma_f32_16x16x32_bf16(vf, pf[ks], o[dd], 0, 0, 0);
            }
        }
        __builtin_amdgcn_s_setprio(0);
        __syncthreads();
    }

    // ---- parity combine (exact: no-max softmax partial sums add) ----
    // Ks is dead; reuse as f32 exchange. 17 floats/lane, odd stride => 2-way.
    float* xch = (float*)Ks;
    if (par) {
        float* d = xch + (size_t)(g * 64 + lane) * 17;
#pragma unroll
        for (int dd = 0; dd < 4; ++dd)
#pragma unroll
            for (int r2 = 0; r2 < 4; ++r2) d[dd * 4 + r2] = o[dd][r2];
        d[16] = lacc;
    }
    __syncthreads();
    if (!par) {
        const float* d = xch + (size_t)(g * 64 + lane) * 17;
#pragma unroll
        for (int dd = 0; dd < 4; ++dd)
#pragma unroll
            for (int r2 = 0; r2 < 4; ++r2) o[dd][r2] += d[dd * 4 + r2];
        lacc += d[16];

        // reduce l across the 4 q4 groups (keys were split across q4)
        lacc += __shfl_xor(lacc, 16);
        lacc += __shfl_xor(lacc, 32);
        const float inv = 1.0f / lacc;

        // O^T layout: q = l16 (one row per lane), d = dd*16 + q4*4 + r
        unsigned short* orow =
            O + (size_t)(b * LQ + q0 + g * 16 + l16) * INNER + h * DH + q4 * 4;
#pragma unroll
        for (int dd = 0; dd < 4; ++dd) {
            ushort4 u;
            u.x = f2bf(o[dd][0] * inv); u.y = f2bf(o[dd][1] * inv);
            u.z = f2bf(o[dd][2] * inv); u.w = f2bf(o[dd][3] * inv);
            *(ushort4*)(orow + dd * 16) = u;
        }
    }
}

extern "C" void kernel_launch(void* const* d_in, const int* in_sizes, int n_in,
                              void* d_out, int out_size, void* d_ws, size_t ws_size,
                              hipStream_t stream) {
    const float* x    = (const float*)d_in[0];
    const float* y    = (const float*)d_in[1];
    const float* mask = (const float*)d_in[2];
    const float* Wq   = (const float*)d_in[3];
    const float* Wk   = (const float*)d_in[4];
    const float* Wv   = (const float*)d_in[5];
    const float* Wo   = (const float*)d_in[6];
    float* out = (float*)d_out;

    const size_t NX = (size_t)BATCH * LQ * DIM;    // 4.19M
    const size_t NS = (size_t)BATCH * LQ * INNER;  // 2.10M
    const size_t NW = (size_t)INNER * DIM;         // 0.52M
    unsigned short* xb  = (unsigned short*)d_ws;
    unsigned short* yb  = xb + NX;
    unsigned short* qb  = yb + NX;
    unsigned short* kb  = qb + NS;
    unsigned short* vt  = kb + NS;
    unsigned short* wqb = vt + NS;
    unsigned short* wkb = wqb + NW;
    unsigned short* wvb = wkb + NW;
    unsigned short* wob = wvb + NW;
    unsigned long long* mbits = (unsigned long long*)(wob + NW);
    unsigned short* ao  = xb;   // xb dead after proj
    // ws: 33.8 MB bf16 + 1 MB bits

    dim3 blk(256);
    prep<<<dim3(1024, 7), blk, 0, stream>>>(
        x, y, Wq, Wk, Wv, Wo, mask, xb, yb, wqb, wkb, wvb, wob, mbits);
    proj_qkv<<<dim3(4096 / 128, INNER / 128, 3), dim3(512), 0, stream>>>(
        xb, yb, wqb, wkb, wvb, qb, kb, vt);
    attn_mfma<<<dim3(512), dim3(512), 0, stream>>>(
        qb, kb, vt, mbits, ao);
    gemm_out<<<dim3(4096 / 128, DIM / 128), dim3(512), 0, stream>>>(ao, wob, out);
}

// Round 11
// 173.993 us; speedup vs baseline: 1.5059x; 1.0003x over previous
//
#include <hip/hip_runtime.h>
#include <hip/hip_bf16.h>
#include <stdint.h>

#define BATCH 2
#define LQ 2048
#define LK 2048
#define DIM 1024
#define HEADS 8
#define DH 64
#define INNER 512  // HEADS*DH

typedef __attribute__((ext_vector_type(8))) short short8;
typedef __attribute__((ext_vector_type(4))) float f32x4;
typedef __attribute__((ext_vector_type(16))) float f32x16;

__device__ __forceinline__ float bf2f(unsigned short u) {
    union { unsigned int i; float f; } v;
    v.i = ((unsigned int)u) << 16;
    return v.f;
}
__device__ __forceinline__ unsigned short f2bf(float f) {
    __hip_bfloat16 h = __float2bfloat16(f);
    return *reinterpret_cast<unsigned short*>(&h);
}
// raw v_exp_f32 (2^x); __expf would add a *log2e mul we fold into QSCALE
__device__ __forceinline__ float fexp2(float x) {
#if __has_builtin(__builtin_amdgcn_exp2f)
    return __builtin_amdgcn_exp2f(x);
#else
    return __expf(x * 0.69314718056f);
#endif
}
__device__ __forceinline__ void stc(unsigned short* C, size_t i, float v) { C[i] = f2bf(v); }
__device__ __forceinline__ void stc(float* C, size_t i, float v) { C[i] = v; }

// packed f32x2 -> bf16x2 (RNE), single instruction (T12 recipe; no builtin)
__device__ __forceinline__ unsigned cvtpk_bf16(float lo, float hi) {
    unsigned r;
    asm("v_cvt_pk_bf16_f32 %0, %1, %2" : "=v"(r) : "v"(lo), "v"(hi));
    return r;
}
// permlane32_swap: x' = [x_lo32 | y_lo32], y' = [x_hi32 | y_hi32]
__device__ __forceinline__ void perm32swap(unsigned& a, unsigned& b) {
#if __has_builtin(__builtin_amdgcn_permlane32_swap)
    auto r = __builtin_amdgcn_permlane32_swap(a, b, false, false);
    a = r[0]; b = r[1];
#else
    asm volatile("v_permlane32_swap_b32 %0, %1" : "+v"(a), "+v"(b));
#endif
}

// Direct global->LDS DMA, 16B/lane. LDS dest = wave-uniform base + lane*16.
typedef __attribute__((address_space(1))) const unsigned int gu32;
typedef __attribute__((address_space(3))) unsigned int lu32;
__device__ __forceinline__ void gload16(const void* g, void* l) {
    __builtin_amdgcn_global_load_lds((gu32*)g, (lu32*)l, 16, 0, 0);
}

// ---------------------------------------------------------------------------
// prep: fp32->bf16 copies (y=0..5, scalar RNE cvt) + mask bit-pack (y=6),
// one launch. (unchanged this round)
// ---------------------------------------------------------------------------
__global__ __launch_bounds__(256) void prep(
    const float* __restrict__ x,  const float* __restrict__ y,
    const float* __restrict__ wq, const float* __restrict__ wk,
    const float* __restrict__ wv, const float* __restrict__ wo,
    const float* __restrict__ mask,
    unsigned short* __restrict__ xb,  unsigned short* __restrict__ yb,
    unsigned short* __restrict__ wqb, unsigned short* __restrict__ wkb,
    unsigned short* __restrict__ wvb, unsigned short* __restrict__ wob,
    unsigned long long* __restrict__ mbits)
{
    if (blockIdx.y == 6) {
        const int wid = blockIdx.x * 4 + (threadIdx.x >> 6);   // 4096 waves
        const int lane = threadIdx.x & 63;
        for (int task = wid; task < BATCH * LQ * 8; task += 4096) {
            int row = task >> 3, g = task & 7;
            const float* mp = mask + (size_t)row * LK + g * 256;
            unsigned long long* ob = mbits + (size_t)row * (LK / 64) + g * 4;
            float v0 = mp[0 * 64 + lane];
            float v1 = mp[1 * 64 + lane];
            float v2 = mp[2 * 64 + lane];
            float v3 = mp[3 * 64 + lane];
            unsigned long long b0 = __ballot(v0 > 0.5f);
            unsigned long long b1 = __ballot(v1 > 0.5f);
            unsigned long long b2 = __ballot(v2 > 0.5f);
            unsigned long long b3 = __ballot(v3 > 0.5f);
            if (lane == 0) { ob[0] = b0; ob[1] = b1; ob[2] = b2; ob[3] = b3; }
        }
        return;
    }
    const float* src; unsigned short* dst; int n4;
    switch (blockIdx.y) {
        case 0: src = x;  dst = xb;  n4 = (BATCH * LQ * DIM) / 4; break;
        case 1: src = y;  dst = yb;  n4 = (BATCH * LK * DIM) / 4; break;
        case 2: src = wq; dst = wqb; n4 = (INNER * DIM) / 4; break;
        case 3: src = wk; dst = wkb; n4 = (INNER * DIM) / 4; break;
        case 4: src = wv; dst = wvb; n4 = (INNER * DIM) / 4; break;
        default: src = wo; dst = wob; n4 = (INNER * DIM) / 4; break;
    }
    const int stride = gridDim.x * 256;
    for (int i = blockIdx.x * 256 + threadIdx.x; i < n4; i += stride) {
        float4 f = ((const float4*)src)[i];
        ushort4 u;
        u.x = f2bf(f.x); u.y = f2bf(f.y); u.z = f2bf(f.z); u.w = f2bf(f.w);
        ((ushort4*)dst)[i] = u;
    }
}

// ---------------------------------------------------------------------------
// C = scale * (A[M,K] @ W[N,K]^T), bf16 in, fp32 accum.
// 128x128 tile, 8 waves (2x4), BK=64, swizzled global_load_lds staging,
// double-buffered, one barrier/K-tile. (unchanged this round)
// ---------------------------------------------------------------------------
template <int IM, int JN, int WR, int WC, typename TC, int EPI>
__device__ __forceinline__ void gemm_body(
    const unsigned short* __restrict__ A,
    const unsigned short* __restrict__ W,
    TC* __restrict__ C,
    int K, int N, float scale,
    unsigned short* SH)
{
    constexpr int THREADS = WR * WC * 64;
    constexpr int BM = WR * IM * 16;
    constexpr int BN = WC * JN * 16;
    constexpr int ACH = BM * 8;     // 16B chunks per A tile
    constexpr int BCH = BN * 8;
    constexpr int AUS = BM * 64;    // shorts per A buffer
    constexpr int BUS = BN * 64;

    unsigned short* As = SH;
    unsigned short* Bs = SH + 2 * AUS;

    const int tid = threadIdx.x;
    const int m0 = blockIdx.x * BM;
    const int n0 = blockIdx.y * BN;
    const int w = tid >> 6, lane = tid & 63;
    const int q4 = lane >> 4, l16 = lane & 15;
    const int wm = (w / WC) * (IM * 16), wn = (w % WC) * (JN * 16);
    const int sw = l16 & 7;

    f32x4 acc[IM][JN] = {};

#pragma unroll
    for (int i = 0; i < ACH / THREADS; ++i) {
        int s = tid + i * THREADS;
        int r = s >> 3, ch = (s & 7) ^ (r & 7);
        gload16(A + (size_t)(m0 + r) * K + ch * 8, As + (size_t)s * 8);
    }
#pragma unroll
    for (int i = 0; i < BCH / THREADS; ++i) {
        int s = tid + i * THREADS;
        int r = s >> 3, ch = (s & 7) ^ (r & 7);
        gload16(W + (size_t)(n0 + r) * K + ch * 8, Bs + (size_t)s * 8);
    }
    __syncthreads();

    const int nt = K / 64;
    for (int t = 0; t < nt; ++t) {
        const int curA = (t & 1) * AUS;
        const int curB = (t & 1) * BUS;
        if (t + 1 < nt) {
            int kk = (t + 1) * 64;
            const int nxtA = AUS - curA, nxtB = BUS - curB;
#pragma unroll
            for (int i = 0; i < ACH / THREADS; ++i) {
                int s = tid + i * THREADS;
                int r = s >> 3, ch = (s & 7) ^ (r & 7);
                gload16(A + (size_t)(m0 + r) * K + kk + ch * 8, As + nxtA + (size_t)s * 8);
            }
#pragma unroll
            for (int i = 0; i < BCH / THREADS; ++i) {
                int s = tid + i * THREADS;
                int r = s >> 3, ch = (s & 7) ^ (r & 7);
                gload16(W + (size_t)(n0 + r) * K + kk + ch * 8, Bs + nxtB + (size_t)s * 8);
            }
        }

#pragma unroll
        for (int ks = 0; ks < 2; ++ks) {
            const int kq = ((ks * 4 + q4) ^ sw) * 8;
            short8 a[IM], b[JN];
#pragma unroll
            for (int i = 0; i < IM; ++i)
                a[i] = *(const short8*)(As + curA + (wm + i * 16 + l16) * 64 + kq);
#pragma unroll
            for (int j = 0; j < JN; ++j)
                b[j] = *(const short8*)(Bs + curB + (wn + j * 16 + l16) * 64 + kq);
#pragma unroll
            for (int i = 0; i < IM; ++i)
#pragma unroll
                for (int j = 0; j < JN; ++j)
                    acc[i][j] = __builtin_amdgcn_mfma_f32_16x16x32_bf16(
                        a[i], b[j], acc[i][j], 0, 0, 0);
        }
        __syncthreads();
    }

    if (EPI == 0) {
        // C/D layout: col = lane&15, row = quad*4 + reg  [m89-verified]
#pragma unroll
        for (int i = 0; i < IM; ++i)
#pragma unroll
            for (int j = 0; j < JN; ++j)
#pragma unroll
                for (int r = 0; r < 4; ++r) {
                    int row = m0 + wm + i * 16 + q4 * 4 + r;
                    int col = n0 + wn + j * 16 + l16;
                    stc(C, (size_t)row * N + col, acc[i][j][r] * scale);
                }
    } else {
        // V-transpose epilogue into vt[((b*H+h)*DH+d)*LK + key].
        constexpr int KW = IM * 16;
        constexpr int DW = JN * 16;
        constexpr int TPS = KW + 8;
        unsigned short* TP = SH + w * (DW * TPS);
#pragma unroll
        for (int i = 0; i < IM; ++i)
#pragma unroll
            for (int j = 0; j < JN; ++j) {
                ushort4 u;
                u.x = f2bf(acc[i][j][0]); u.y = f2bf(acc[i][j][1]);
                u.z = f2bf(acc[i][j][2]); u.w = f2bf(acc[i][j][3]);
                *(ushort4*)(TP + (j * 16 + l16) * TPS + i * 16 + q4 * 4) = u;
            }
        const int keyflat = m0 + wm;
        const int bb = keyflat >> 11, key0 = keyflat & (LK - 1);
        const int hh = (n0 + wn) >> 6;
        const int dlow = (n0 + wn) & 63;
        constexpr int RCH = KW / 8;
        constexpr int NCH = DW * RCH;
#pragma unroll
        for (int p = 0; p < NCH / 64; ++p) {
            int c = p * 64 + lane;
            int dl = c / RCH, kc = c % RCH;
            uint4 v = *(const uint4*)(TP + dl * TPS + kc * 8);
            *(uint4*)((unsigned short*)C +
                ((size_t)((bb * HEADS + hh) * DH + dlow + dl)) * LK + key0 + kc * 8) = v;
        }
    }
}

// q scaled by 0.125*log2(e) so attn uses raw v_exp_f32 (2^x) directly.
#define QSCALE 0.18033688011112042f

__global__ __launch_bounds__(512) void proj_qkv(
    const unsigned short* __restrict__ xb, const unsigned short* __restrict__ yb,
    const unsigned short* __restrict__ wqb, const unsigned short* __restrict__ wkb,
    const unsigned short* __restrict__ wvb,
    unsigned short* __restrict__ qb, unsigned short* __restrict__ kb,
    unsigned short* __restrict__ vt)
{
    __shared__ __align__(16) unsigned short SH[4 * 128 * 64];  // 64 KB
    const int z = blockIdx.z;
    const unsigned short* A = (z == 0) ? xb : yb;
    const unsigned short* W = (z == 0) ? wqb : (z == 1) ? wkb : wvb;
    if (z == 2)
        gemm_body<4, 2, 2, 4, unsigned short, 1>(A, W, vt, DIM, INNER, 1.0f, SH);
    else
        gemm_body<4, 2, 2, 4, unsigned short, 0>(A, W, (z == 0) ? qb : kb, DIM, INNER,
                                                 (z == 0) ? QSCALE : 1.0f, SH);
}

__global__ __launch_bounds__(512) void gemm_out(
    const unsigned short* __restrict__ A,
    const unsigned short* __restrict__ W,
    float* __restrict__ C)
{
    __shared__ __align__(16) unsigned short SH[4 * 128 * 64];  // 64 KB
    gemm_body<4, 2, 2, 4, float, 0>(A, W, C, INNER, DIM, 1.0f, SH);
}

// ---------------------------------------------------------------------------
// Flash attention v7: 32x32x16 MFMA (2x FLOP per ds_read vs 16x16x32 -- the
// measured dominant pipe). Same occupancy shape as v3/v6: 512 thr, 8 waves,
// 64 KB LDS, 512 blocks (2/CU), T1 h=bid&7 decode, T5 setprio.
// Wave = (qh: 32-q half) x (kh: 32-key half) x (par: tile parity).
// S^T = mfma32(K,Q): lane col q = l&31, keys kl(r) = (r&3)+8*(r>>2)+4*hl
// [m74/m101-verified D layout], hl = l>>5. Mask nibble for r-group g:
// (mrow>>kh*32 >> (8g+4hl)) & 0xF. PV B-frag (16 keys/kstep): lane needs
// keys 8hl..8hl+7: built from cvtpk pairs pk[2g]={kl(4g),kl(4g+1)},
// pk[2g+1]={kl(4g+2),kl(4g+3)} via perm32swap(pk[4k],pk[4k+2]) -> (reg0,
// reg2), perm32swap(pk[4k+1],pk[4k+3]) -> (reg1,reg3). Only 4 swaps.
// O^T = mfma32(V^T, P^T): d = df*32 + kl(r). 4-way partial combine
// (kh x par) through dead LDS, lacc also shfl_xor(32) (hl halves).
// ---------------------------------------------------------------------------
#define AT_SLOT (64 * 64)

__global__ __launch_bounds__(512, 4) void attn_mfma(
    const unsigned short* __restrict__ Q,
    const unsigned short* __restrict__ Kb,
    const unsigned short* __restrict__ Vt,
    const unsigned long long* __restrict__ Mb,
    unsigned short* __restrict__ O)
{
    __shared__ __align__(16) unsigned short Ks[4 * AT_SLOT];   // 32 KB
    __shared__ __align__(16) unsigned short Vs[4 * AT_SLOT];   // 32 KB

    const int tid = threadIdx.x;
    const int L = blockIdx.x;
    const int h = L & 7;                      // T1: head == XCD slot
    const int jj = L >> 3;                    // 0..63
    const int b = jj >> 5;                    // batch
    const int q0 = (jj & 31) * 64;            // q-block
    const int w = tid >> 6, lane = tid & 63;
    const int qh = w & 1;                     // 32-q half
    const int kh = (w >> 1) & 1;              // 32-key half
    const int par = w >> 2;                   // tile parity
    const int l31 = lane & 31, hl = lane >> 5;

    // Q as B-operand frags (32x32x16): col q = l31, k-window = ks*16+8*hl
    short8 qf[4];
    {
        const unsigned short* qp =
            Q + (size_t)(b * LQ + q0 + qh * 32 + l31) * INNER + h * DH + 8 * hl;
#pragma unroll
        for (int ks = 0; ks < 4; ++ks)
            qf[ks] = *(const short8*)(qp + ks * 16);
    }

    f32x16 o[2] = {};
    float lacc = 0.f;

    const unsigned short* kbase = Kb + (size_t)(b * LK) * INNER + h * DH;
    const unsigned short* vbase = Vt + (size_t)((b * HEADS + h) * DH) * LK;
    const unsigned long long* mrow =
        Mb + (size_t)(b * LQ + q0 + qh * 32 + l31) * (LK / 64);

    // staging coords (unchanged): 512 threads stage one 64x64 tile/gload16
    const int rr = tid >> 3;
    const int ch = (tid & 7) ^ (rr & 7);

#pragma unroll
    for (int tn = 0; tn < 2; ++tn) {
        gload16(kbase + (size_t)(tn * 64 + rr) * INNER + ch * 8,
                Ks + tn * AT_SLOT + (size_t)tid * 8);
        gload16(vbase + (size_t)rr * LK + tn * 64 + ch * 8,
                Vs + tn * AT_SLOT + (size_t)tid * 8);
    }
    __syncthreads();

    const int l7 = lane & 7;
    const int NR = LK / 128;   // 16 rounds, 2 tiles each
    for (int rd = 0; rd < NR; ++rd) {
        if (rd + 1 < NR) {
#pragma unroll
            for (int i = 0; i < 2; ++i) {
                const int tn = 2 * rd + 2 + i;
                const int sl = tn & 3;
                gload16(kbase + (size_t)(tn * 64 + rr) * INNER + ch * 8,
                        Ks + sl * AT_SLOT + (size_t)tid * 8);
                gload16(vbase + (size_t)rr * LK + tn * 64 + ch * 8,
                        Vs + sl * AT_SLOT + (size_t)tid * 8);
            }
        }
        const int t = 2 * rd + par;
        const int cur = (t & 3) * AT_SLOT;

        // ---- S^T = K Q^T : one 32x32 acc over 4 ksteps ----
        f32x16 s = {};
        __builtin_amdgcn_s_setprio(1);
#pragma unroll
        for (int ks = 0; ks < 4; ++ks) {
            const int R = kh * 32 + l31;             // key row in tile
            const int c0 = ks * 2 + hl;              // 8-elem k-chunk
            short8 kf = *(const short8*)(Ks + cur + R * 64 + ((c0 ^ l7) * 8));
            s = __builtin_amdgcn_mfma_f32_32x32x16_bf16(kf, qf[ks], s, 0, 0, 0);
        }
        __builtin_amdgcn_s_setprio(0);

        // ---- p = masked ? 0 : 2^s ; cvtpk pairs ----
        unsigned bits32 = (unsigned)(mrow[t] >> (kh * 32));
        unsigned pk[8];
#pragma unroll
        for (int g = 0; g < 4; ++g) {
            unsigned nib = (bits32 >> (8 * g + 4 * hl)) & 0xFu;
            float p0 = (nib & 1u) ? 0.f : fexp2(s[4 * g + 0]);
            float p1 = (nib & 2u) ? 0.f : fexp2(s[4 * g + 1]);
            float p2 = (nib & 4u) ? 0.f : fexp2(s[4 * g + 2]);
            float p3 = (nib & 8u) ? 0.f : fexp2(s[4 * g + 3]);
            lacc += (p0 + p1) + (p2 + p3);
            pk[2 * g]     = cvtpk_bf16(p0, p1);
            pk[2 * g + 1] = cvtpk_bf16(p2, p3);
        }

        // ---- P^T B-frags via permlane32 (no LDS) ----
        short8 pf[2];
#pragma unroll
        for (int k2 = 0; k2 < 2; ++k2) {
            unsigned r0 = pk[4 * k2 + 0], r2 = pk[4 * k2 + 2];
            unsigned r1 = pk[4 * k2 + 1], r3 = pk[4 * k2 + 3];
            perm32swap(r0, r2);   // r0 -> reg0, r2 -> reg2
            perm32swap(r1, r3);   // r1 -> reg1, r3 -> reg3
            union { unsigned u[4]; short8 s8; } up;
            up.u[0] = r0; up.u[1] = r1; up.u[2] = r2; up.u[3] = r3;
            pf[k2] = up.s8;
        }

        // ---- O^T += V^T P^T over this wave's 32 keys ----
        __builtin_amdgcn_s_setprio(1);
#pragma unroll
        for (int df = 0; df < 2; ++df) {
#pragma unroll
            for (int k2 = 0; k2 < 2; ++k2) {
                const int R = df * 32 + l31;             // d row
                const int c0 = kh * 4 + k2 * 2 + hl;     // key chunk in tile
                short8 vf = *(const short8*)(Vs + cur + R * 64 + ((c0 ^ l7) * 8));
                o[df] = __builtin_amdgcn_mfma_f32_32x32x16_bf16(vf, pf[k2], o[df], 0, 0, 0);
            }
        }
        __builtin_amdgcn_s_setprio(0);
        __syncthreads();
    }

    // ---- 4-way partial combine (kh x par) per qh through dead LDS ----
    // stride 33 floats (odd) => conflict-free. per qh: 3*64*33*4 = 25344 B.
    float* xq = (float*)(qh ? (void*)Vs : (void*)Ks);
    const int wslot = par * 2 + kh;          // 0 = leader
    if (wslot) {
        float* d = xq + (size_t)((wslot - 1) * 64 + lane) * 33;
#pragma unroll
        for (int df = 0; df < 2; ++df)
#pragma unroll
            for (int r = 0; r < 16; ++r) d[df * 16 + r] = o[df][r];
        d[32] = lacc;
    }
    __syncthreads();
    if (!wslot) {
#pragma unroll
        for (int ws2 = 0; ws2 < 3; ++ws2) {
            const float* d = xq + (size_t)(ws2 * 64 + lane) * 33;
#pragma unroll
            for (int df = 0; df < 2; ++df)
#pragma unroll
                for (int r = 0; r < 16; ++r) o[df][r] += d[df * 16 + r];
            lacc += d[32];
        }
        // hl halves hold disjoint key sets for the same q
        lacc += __shfl_xor(lacc, 32);
        const float inv = 1.0f / lacc;

        // store: q = l31 row; d = df*32 + 8g + 4hl + (0..3)  (r = 4g..4g+3)
        unsigned short* orow =
            O + (size_t)(b * LQ + q0 + qh * 32 + l31) * INNER + h * DH;
#pragma unroll
        for (int df = 0; df < 2; ++df)
#pragma unroll
            for (int g = 0; g < 4; ++g) {
                ushort4 u;
                u.x = f2bf(o[df][4 * g + 0] * inv);
                u.y = f2bf(o[df][4 * g + 1] * inv);
                u.z = f2bf(o[df][4 * g + 2] * inv);
                u.w = f2bf(o[df][4 * g + 3] * inv);
                *(ushort4*)(orow + df * 32 + 8 * g + 4 * hl) = u;
            }
    }
}

extern "C" void kernel_launch(void* const* d_in, const int* in_sizes, int n_in,
                              void* d_out, int out_size, void* d_ws, size_t ws_size,
                              hipStream_t stream) {
    const float* x    = (const float*)d_in[0];
    const float* y    = (const float*)d_in[1];
    const float* mask = (const float*)d_in[2];
    const float* Wq   = (const float*)d_in[3];
    const float* Wk   = (const float*)d_in[4];
    const float* Wv   = (const float*)d_in[5];
    const float* Wo   = (const float*)d_in[6];
    float* out = (float*)d_out;

    const size_t NX = (size_t)BATCH * LQ * DIM;    // 4.19M
    const size_t NS = (size_t)BATCH * LQ * INNER;  // 2.10M
    const size_t NW = (size_t)INNER * DIM;         // 0.52M
    unsigned short* xb  = (unsigned short*)d_ws;
    unsigned short* yb  = xb + NX;
    unsigned short* qb  = yb + NX;
    unsigned short* kb  = qb + NS;
    unsigned short* vt  = kb + NS;
    unsigned short* wqb = vt + NS;
    unsigned short* wkb = wqb + NW;
    unsigned short* wvb = wkb + NW;
    unsigned short* wob = wvb + NW;
    unsigned long long* mbits = (unsigned long long*)(wob + NW);
    unsigned short* ao  = xb;   // xb dead after proj
    // ws: 33.8 MB bf16 + 1 MB bits

    dim3 blk(256);
    prep<<<dim3(1024, 7), blk, 0, stream>>>(
        x, y, Wq, Wk, Wv, Wo, mask, xb, yb, wqb, wkb, wvb, wob, mbits);
    proj_qkv<<<dim3(4096 / 128, INNER / 128, 3), dim3(512), 0, stream>>>(
        xb, yb, wqb, wkb, wvb, qb, kb, vt);
    attn_mfma<<<dim3(512), dim3(512), 0, stream>>>(
        qb, kb, vt, mbits, ao);
    gemm_out<<<dim3(4096 / 128, DIM / 128), dim3(512), 0, stream>>>(ao, wob, out);
}